// Round 4
// baseline (1827.378 us; speedup 1.0000x reference)
//
#include <hip/hip_runtime.h>

#define NNODES 800000
#define CINC   32
#define COUTC  64
#define KT     27
#define EPSV   1e-5f

typedef _Float16 half8 __attribute__((ext_vector_type(8)));
typedef _Float16 half4 __attribute__((ext_vector_type(4)));
typedef float    f32x4 __attribute__((ext_vector_type(4)));

#define MFMA(A, B, C) __builtin_amdgcn_mfma_f32_16x16x32_f16((A), (B), (C), 0, 0, 0)
#define SBAR()  __builtin_amdgcn_s_barrier()
#define SCHED() __builtin_amdgcn_sched_barrier(0)

// Async global->LDS, 16 B per lane: global src per-lane, LDS dst uniform+lane*16.
__device__ __forceinline__ void gl2lds(const _Float16* g, _Float16* l) {
  __builtin_amdgcn_global_load_lds(
      (const __attribute__((address_space(1))) void*)g,
      (__attribute__((address_space(3))) void*)l, 16, 0, 0);
}

// ---------------------------------------------------------------------------
// GroupNorm over one lane-local group of 4 channels (matches jnp reference).
// ---------------------------------------------------------------------------
__device__ __forceinline__ f32x4 gn4(f32x4 v, const float* __restrict__ w,
                                     const float* __restrict__ b, int cb) {
  const float mu = (v[0] + v[1] + v[2] + v[3]) * 0.25f;
  f32x4 d;
#pragma unroll
  for (int j = 0; j < 4; ++j) d[j] = v[j] - mu;
  const float var = (d[0] * d[0] + d[1] * d[1] + d[2] * d[2] + d[3] * d[3]) * 0.25f;
  const float rs = 1.0f / sqrtf(var + EPSV);
  const f32x4 wv = *(const f32x4*)(w + cb);
  const f32x4 bv = *(const f32x4*)(b + cb);
  f32x4 r;
#pragma unroll
  for (int j = 0; j < 4; ++j) r[j] = d[j] * rs * wv[j] + bv[j];
  return r;
}

// ---------------------------------------------------------------------------
// Prepass 1: split f32 -> f16 hi + lo, packed per node (128 B row).
// ---------------------------------------------------------------------------
__global__ __launch_bounds__(256) void k_split(const float* __restrict__ x,
                                               _Float16* __restrict__ dpk, int n4) {
  const int i = blockIdx.x * 256 + threadIdx.x;
  if (i >= n4) return;
  const f32x4 v = ((const f32x4*)x)[i];
  half4 h, l;
#pragma unroll
  for (int j = 0; j < 4; ++j) {
    h[j] = (_Float16)v[j];
    l[j] = (_Float16)(v[j] - (float)h[j]);
  }
  const int n = i >> 3, g = i & 7;
  *(half4*)(dpk + (size_t)n * 64 + g * 4) = h;
  *(half4*)(dpk + (size_t)n * 64 + 32 + g * 4) = l;
}

// ---------------------------------------------------------------------------
// Prepass 2: pre-swizzle weights into MFMA A-operand image layout.
// waT: [27][t:4][h:2][lane:64][8]  wbT: [27][t:4][kc:2][h:2][lane:64][8]
// ---------------------------------------------------------------------------
__global__ __launch_bounds__(256) void k_prepw(const float* __restrict__ Wa,
                                               const float* __restrict__ Wb,
                                               const float* __restrict__ W1,
                                               _Float16* __restrict__ waT,
                                               _Float16* __restrict__ wbT,
                                               _Float16* __restrict__ w1T) {
  const int u = blockIdx.x * 256 + threadIdx.x;
  const float* s;
  _Float16* d;
  size_t db;
  int cin0, cout;
  if (u < 6912) {
    const int tap = u >> 8, r = u & 255, t = r >> 6, l = r & 63;
    cin0 = (l >> 4) * 8;
    cout = t * 16 + (l & 15);
    s = Wa + (size_t)tap * CINC * COUTC;
    d = waT;
    db = ((size_t)(tap * 8 + t * 2) * 64 + l) * 8;
  } else if (u < 20736) {
    const int u2 = u - 6912;
    const int tap = u2 >> 9, r = u2 & 511, t = r >> 7, r2 = r & 127;
    const int kc = r2 >> 6, l = r2 & 63;
    cin0 = kc * 32 + (l >> 4) * 8;
    cout = t * 16 + (l & 15);
    s = Wb + (size_t)tap * COUTC * COUTC;
    d = wbT;
    db = ((size_t)(tap * 16 + t * 4 + kc * 2) * 64 + l) * 8;
  } else if (u < 20992) {
    const int u3 = u - 20736, t = u3 >> 6, l = u3 & 63;
    cin0 = (l >> 4) * 8;
    cout = t * 16 + (l & 15);
    s = W1;
    d = w1T;
    db = ((size_t)(t * 2) * 64 + l) * 8;
  } else {
    return;
  }
  half8 h, l8;
#pragma unroll
  for (int j = 0; j < 8; ++j) {
    const float v = s[(size_t)(cin0 + j) * COUTC + cout];
    h[j] = (_Float16)v;
    l8[j] = (_Float16)(v - (float)h[j]);
  }
  *(half8*)(d + db) = h;
  *(half8*)(d + db + 512) = l8;
}

// ===========================================================================
// Kernel A: h = relu(GN(conv(data, Wa))) -> SEPARATE hhi / hlo planes.
// Depth-3 gather prefetch (4 rotating VGPR buffers) + 3 LDS weight slots.
// vmcnt retire-set per step t: {G(t+1),st(t+1),G(t+2),st(t+2),G(t+3)} = 16.
// All phase edges pinned with sched_barrier(0).
// ===========================================================================
#define STAGEA(T, SL)                                                          \
  {                                                                            \
    const _Float16* sp_ = waT + (size_t)(T)*4096 + (wave * 2) * 512 + lane * 8;\
    _Float16* dp_ = s_w + (SL)*4096 + (wave * 2) * 512;                        \
    gl2lds(sp_, dp_);                                                          \
    gl2lds(sp_ + 512, dp_ + 512);                                              \
  }

#define GATHA(T, GB)                                                           \
  {                                                                            \
    const int i0_ = s_n[ln0 * KT + (T)];                                       \
    const int i1_ = s_n[(ln0 + 16) * KT + (T)];                                \
    const _Float16* p0_ = dpk + (size_t)i0_ * 64 + q * 8;                      \
    const _Float16* p1_ = dpk + (size_t)i1_ * 64 + q * 8;                      \
    GB[0] = *(const half8*)(p0_);                                              \
    GB[1] = *(const half8*)(p0_ + 32);                                         \
    GB[2] = *(const half8*)(p1_);                                              \
    GB[3] = *(const half8*)(p1_ + 32);                                         \
  }

// RS = read slot (T%3), WS = stage slot ((T+2)%3), GBC = consume, GBN = fill.
#define STEPA(T, RS, WS, GBC, GBN, VMS, DOSTAGE, DOG)                          \
  {                                                                            \
    SCHED();                                                                   \
    SBAR();                                                                    \
    SCHED();                                                                   \
    if (DOSTAGE) STAGEA((T) + 2, WS);                                          \
    if (DOG) GATHA((T) + 3, GBN);                                              \
    asm volatile("s_waitcnt vmcnt(" VMS ")" ::: "memory");                     \
    SCHED();                                                                   \
    SBAR();                                                                    \
    SCHED();                                                                   \
    _Pragma("unroll") for (int t4 = 0; t4 < 4; ++t4) {                         \
      const _Float16* wb_ = s_w + (RS)*4096 + (t4 * 2) * 512 + lane * 8;       \
      const half8 wh_ = *(const half8*)(wb_);                                  \
      const half8 wl_ = *(const half8*)(wb_ + 512);                            \
      acc[t4][0] = MFMA(wh_, GBC[0], acc[t4][0]);                              \
      acc[t4][0] = MFMA(wh_, GBC[1], acc[t4][0]);                              \
      acc[t4][0] = MFMA(wl_, GBC[0], acc[t4][0]);                              \
      acc[t4][1] = MFMA(wh_, GBC[2], acc[t4][1]);                              \
      acc[t4][1] = MFMA(wh_, GBC[3], acc[t4][1]);                              \
      acc[t4][1] = MFMA(wl_, GBC[2], acc[t4][1]);                              \
    }                                                                          \
  }

__global__ __launch_bounds__(256, 4) void k_conva(
    const _Float16* __restrict__ dpk, const int* __restrict__ neigh,
    const _Float16* __restrict__ waT, const float* __restrict__ gw,
    const float* __restrict__ gb, _Float16* __restrict__ hhi,
    _Float16* __restrict__ hlo) {
  __shared__ int s_n[128 * KT];
  __shared__ _Float16 s_w[3 * 4096];  // 3 slots x 8 KB
  const int tid = threadIdx.x;
  const int wave = tid >> 6, lane = tid & 63;
  const int cl = lane & 15, q = lane >> 4;
  const int node0 = blockIdx.x * 128;

  for (int j = tid; j < 128 * KT; j += 256) s_n[j] = neigh[(size_t)node0 * KT + j];
  __syncthreads();  // full drain; 0 outstanding entering prologue

  f32x4 acc[4][2] = {};
  const int ln0 = wave * 32 + cl;
  half8 g0[4], g1[4], g2[4], g3[4];

  // Prologue (age order matters): st(0)->s0, st(1)->s1, G(0), G(1), G(2).
  STAGEA(0, 0);
  STAGEA(1, 1);
  GATHA(0, g0);
  GATHA(1, g1);
  GATHA(2, g2);

  STEPA(0, 0, 2, g0, g3, "14", 1, 1);
  STEPA(1, 1, 0, g1, g0, "16", 1, 1);
  STEPA(2, 2, 1, g2, g1, "16", 1, 1);
  STEPA(3, 0, 2, g3, g2, "16", 1, 1);
  STEPA(4, 1, 0, g0, g3, "16", 1, 1);
  STEPA(5, 2, 1, g1, g0, "16", 1, 1);
  STEPA(6, 0, 2, g2, g1, "16", 1, 1);
  STEPA(7, 1, 0, g3, g2, "16", 1, 1);
  STEPA(8, 2, 1, g0, g3, "16", 1, 1);
  STEPA(9, 0, 2, g1, g0, "16", 1, 1);
  STEPA(10, 1, 0, g2, g1, "16", 1, 1);
  STEPA(11, 2, 1, g3, g2, "16", 1, 1);
  STEPA(12, 0, 2, g0, g3, "16", 1, 1);
  STEPA(13, 1, 0, g1, g0, "16", 1, 1);
  STEPA(14, 2, 1, g2, g1, "16", 1, 1);
  STEPA(15, 0, 2, g3, g2, "16", 1, 1);
  STEPA(16, 1, 0, g0, g3, "16", 1, 1);
  STEPA(17, 2, 1, g1, g0, "16", 1, 1);
  STEPA(18, 0, 2, g2, g1, "16", 1, 1);
  STEPA(19, 1, 0, g3, g2, "16", 1, 1);
  STEPA(20, 2, 1, g0, g3, "16", 1, 1);
  STEPA(21, 0, 2, g1, g0, "16", 1, 1);
  STEPA(22, 1, 0, g2, g1, "16", 1, 1);
  STEPA(23, 2, 1, g3, g2, "16", 1, 1);
  STEPA(24, 0, 2, g0, g3, "12", 1, 0);  // stage(26)->slot2; no gather
  STEPA(25, 1, 0, g1, g0, "6", 0, 0);
  STEPA(26, 2, 1, g2, g1, "0", 0, 0);

#pragma unroll
  for (int t = 0; t < 4; ++t)
#pragma unroll
    for (int nt = 0; nt < 2; ++nt) {
      const int node = node0 + wave * 32 + nt * 16 + cl;
      const int cb = t * 16 + q * 4;
      const f32x4 g = gn4(acc[t][nt], gw, gb, cb);
      half4 h, l;
#pragma unroll
      for (int j = 0; j < 4; ++j) {
        const float v = fmaxf(g[j], 0.0f);
        h[j] = (_Float16)v;
        l[j] = (_Float16)(v - (float)h[j]);
      }
      *(half4*)(hhi + (size_t)node * 64 + cb) = h;
      *(half4*)(hlo + (size_t)node * 64 + cb) = l;
    }
}

// ===========================================================================
// Kernel B: out = relu(GN(conv(h, Wb)) + GN(data @ W1)) -> f32.
// PASS-SPLIT: loop H gathers ONLY hhi (8 MFMA/tap/t: wh*xh, wl*xh),
// loop L gathers ONLY hlo (4 MFMA/tap/t: wh*xl). Each pass's gather
// working set is 102.4 MB -> L3-resident (fixes the 2.8 GB over-fetch).
// Depth-2, 2 LDS slots per pass; all phase edges pinned.
// ===========================================================================
#define STAGEH(T, SL)                                                          \
  {                                                                            \
    const _Float16* sp_ = wbT + (size_t)(T)*8192 + (wave * 4) * 512 + lane * 8;\
    _Float16* dp_ = s_w + (SL)*8192 + (wave * 4) * 512;                        \
    gl2lds(sp_, dp_);                                                          \
    gl2lds(sp_ + 512, dp_ + 512);                                              \
    gl2lds(sp_ + 1024, dp_ + 1024);                                            \
    gl2lds(sp_ + 1536, dp_ + 1536);                                            \
  }

#define GATHH(T, GB)                                                           \
  {                                                                            \
    const int i0_ = s_n[ln0 * KT + (T)];                                       \
    const int i1_ = s_n[(ln0 + 16) * KT + (T)];                                \
    const _Float16* p0_ = hhi + (size_t)i0_ * 64 + q * 8;                      \
    const _Float16* p1_ = hhi + (size_t)i1_ * 64 + q * 8;                      \
    GB[0] = *(const half8*)(p0_);                                              \
    GB[1] = *(const half8*)(p0_ + 32);                                         \
    GB[2] = *(const half8*)(p1_);                                              \
    GB[3] = *(const half8*)(p1_ + 32);                                         \
  }

#define STEPH(T, S, GBC, GBN, VMS, DOSTAGE, DOG)                               \
  {                                                                            \
    SCHED();                                                                   \
    SBAR();                                                                    \
    SCHED();                                                                   \
    if (DOSTAGE) STAGEH((T) + 1, 1 - (S));                                     \
    if (DOG) GATHH((T) + 2, GBN);                                              \
    asm volatile("s_waitcnt vmcnt(" VMS ")" ::: "memory");                     \
    SCHED();                                                                   \
    SBAR();                                                                    \
    SCHED();                                                                   \
    _Pragma("unroll") for (int t4 = 0; t4 < 4; ++t4) {                         \
      const _Float16* wb_ = s_w + (S)*8192 + (t4 * 4) * 512 + lane * 8;        \
      const half8 wha_ = *(const half8*)(wb_);                                 \
      const half8 wla_ = *(const half8*)(wb_ + 512);                           \
      const half8 whb_ = *(const half8*)(wb_ + 1024);                          \
      const half8 wlb_ = *(const half8*)(wb_ + 1536);                          \
      acc[t4][0] = MFMA(wha_, GBC[0], acc[t4][0]);                             \
      acc[t4][0] = MFMA(wla_, GBC[0], acc[t4][0]);                             \
      acc[t4][0] = MFMA(whb_, GBC[1], acc[t4][0]);                             \
      acc[t4][0] = MFMA(wlb_, GBC[1], acc[t4][0]);                             \
      acc[t4][1] = MFMA(wha_, GBC[2], acc[t4][1]);                             \
      acc[t4][1] = MFMA(wla_, GBC[2], acc[t4][1]);                             \
      acc[t4][1] = MFMA(whb_, GBC[3], acc[t4][1]);                             \
      acc[t4][1] = MFMA(wlb_, GBC[3], acc[t4][1]);                             \
    }                                                                          \
  }

// Loop L: stage only the hi-weight planes (wh) of each tap: chunks
// (t*4+0)*512 and (t*4+2)*512 -> compact slot layout [t:4][kc:2][512].
#define STAGEL(T, SL)                                                          \
  {                                                                            \
    const _Float16* sp_ = wbT + (size_t)(T)*8192 + (wave * 4) * 512 + lane * 8;\
    _Float16* dp_ = s_w + (SL)*4096 + (wave * 2) * 512;                        \
    gl2lds(sp_, dp_);                                                          \
    gl2lds(sp_ + 1024, dp_ + 512);                                             \
  }

#define GATHL(T, GB)                                                           \
  {                                                                            \
    const int i0_ = s_n[ln0 * KT + (T)];                                       \
    const int i1_ = s_n[(ln0 + 16) * KT + (T)];                                \
    const _Float16* p0_ = hlo + (size_t)i0_ * 64 + q * 8;                      \
    const _Float16* p1_ = hlo + (size_t)i1_ * 64 + q * 8;                      \
    GB[0] = *(const half8*)(p0_);                                              \
    GB[1] = *(const half8*)(p0_ + 32);                                         \
    GB[2] = *(const half8*)(p1_);                                              \
    GB[3] = *(const half8*)(p1_ + 32);                                         \
  }

#define STEPL(T, S, GBC, GBN, VMS, DOSTAGE, DOG)                               \
  {                                                                            \
    SCHED();                                                                   \
    SBAR();                                                                    \
    SCHED();                                                                   \
    if (DOSTAGE) STAGEL((T) + 1, 1 - (S));                                     \
    if (DOG) GATHL((T) + 2, GBN);                                              \
    asm volatile("s_waitcnt vmcnt(" VMS ")" ::: "memory");                     \
    SCHED();                                                                   \
    SBAR();                                                                    \
    SCHED();                                                                   \
    _Pragma("unroll") for (int t4 = 0; t4 < 4; ++t4) {                         \
      const _Float16* wb_ = s_w + (S)*4096 + (t4 * 2) * 512 + lane * 8;        \
      const half8 wha_ = *(const half8*)(wb_);                                 \
      const half8 whb_ = *(const half8*)(wb_ + 512);                           \
      acc[t4][0] = MFMA(wha_, GBC[0], acc[t4][0]);                             \
      acc[t4][0] = MFMA(whb_, GBC[1], acc[t4][0]);                             \
      acc[t4][1] = MFMA(wha_, GBC[2], acc[t4][1]);                             \
      acc[t4][1] = MFMA(whb_, GBC[3], acc[t4][1]);                             \
    }                                                                          \
  }

__global__ __launch_bounds__(256, 3) void k_convb(
    const _Float16* __restrict__ hhi, const _Float16* __restrict__ hlo,
    const _Float16* __restrict__ dpk, const int* __restrict__ neigh,
    const _Float16* __restrict__ wbT, const _Float16* __restrict__ w1T,
    const float* __restrict__ gbw, const float* __restrict__ gbb,
    const float* __restrict__ gsw, const float* __restrict__ gsb,
    float* __restrict__ out) {
  __shared__ int s_n[128 * KT];
  __shared__ _Float16 s_w[2 * 8192];  // 2 x 16 KB (loop H); loop L uses 2 x 8 KB
  const int tid = threadIdx.x;
  const int wave = tid >> 6, lane = tid & 63;
  const int cl = lane & 15, q = lane >> 4;
  const int node0 = blockIdx.x * 128;

  for (int j = tid; j < 128 * KT; j += 256) s_n[j] = neigh[(size_t)node0 * KT + j];
  __syncthreads();

  f32x4 acc[4][2] = {};
  const int ln0 = wave * 32 + cl;
  half8 g0[4], g1[4], g2[4];

  // ---- Loop H: hi-activation terms ----
  STAGEH(0, 0);
  GATHH(0, g0);
  GATHH(1, g1);
  for (int c6 = 0; c6 < 24; c6 += 6) {
    STEPH(c6 + 0, 0, g0, g2, "12", 1, 1);
    STEPH(c6 + 1, 1, g1, g0, "12", 1, 1);
    STEPH(c6 + 2, 0, g2, g1, "12", 1, 1);
    STEPH(c6 + 3, 1, g0, g2, "12", 1, 1);
    STEPH(c6 + 4, 0, g1, g0, "12", 1, 1);
    STEPH(c6 + 5, 1, g2, g1, "12", 1, 1);
  }
  STEPH(24, 0, g0, g2, "12", 1, 1);
  STEPH(25, 1, g1, g0, "8", 1, 0);
  STEPH(26, 0, g2, g1, "0", 0, 0);

  // ---- Loop L: lo-activation correction terms ----
  SCHED();
  SBAR();  // all waves done reading s_w slot 0 (loop H step 26)
  SCHED();
  STAGEL(0, 0);
  GATHL(0, g0);
  GATHL(1, g1);
  for (int c6 = 0; c6 < 24; c6 += 6) {
    STEPL(c6 + 0, 0, g0, g2, "10", 1, 1);
    STEPL(c6 + 1, 1, g1, g0, "10", 1, 1);
    STEPL(c6 + 2, 0, g2, g1, "10", 1, 1);
    STEPL(c6 + 3, 1, g0, g2, "10", 1, 1);
    STEPL(c6 + 4, 0, g1, g0, "10", 1, 1);
    STEPL(c6 + 5, 1, g2, g1, "10", 1, 1);
  }
  STEPL(24, 0, g0, g2, "10", 1, 1);
  STEPL(25, 1, g1, g0, "6", 1, 0);
  STEPL(26, 0, g2, g1, "0", 0, 0);

  // Shortcut: sc = data @ W1 (own node).
  f32x4 sc[4][2] = {};
  {
    const int n0g = node0 + wave * 32 + cl;
    const _Float16* p0 = dpk + (size_t)n0g * 64 + q * 8;
    const _Float16* p1 = dpk + (size_t)(n0g + 16) * 64 + q * 8;
    const half8 sh0 = *(const half8*)(p0);
    const half8 sl0 = *(const half8*)(p0 + 32);
    const half8 sh1 = *(const half8*)(p1);
    const half8 sl1 = *(const half8*)(p1 + 32);
    const _Float16* w1p = w1T + lane * 8;
#pragma unroll
    for (int t = 0; t < 4; ++t) {
      const half8 wh = *(const half8*)(w1p + (size_t)(t * 2) * 512);
      const half8 wl = *(const half8*)(w1p + (size_t)(t * 2) * 512 + 512);
      sc[t][0] = MFMA(wh, sh0, sc[t][0]);
      sc[t][0] = MFMA(wh, sl0, sc[t][0]);
      sc[t][0] = MFMA(wl, sh0, sc[t][0]);
      sc[t][1] = MFMA(wh, sh1, sc[t][1]);
      sc[t][1] = MFMA(wh, sl1, sc[t][1]);
      sc[t][1] = MFMA(wl, sh1, sc[t][1]);
    }
  }

#pragma unroll
  for (int t = 0; t < 4; ++t)
#pragma unroll
    for (int nt = 0; nt < 2; ++nt) {
      const int node = node0 + wave * 32 + nt * 16 + cl;
      const int cb = t * 16 + q * 4;
      const f32x4 a = gn4(acc[t][nt], gbw, gbb, cb);
      const f32x4 s = gn4(sc[t][nt], gsw, gsb, cb);
      f32x4 o;
#pragma unroll
      for (int j = 0; j < 4; ++j) o[j] = fmaxf(a[j] + s[j], 0.0f);
      *(f32x4*)(out + (size_t)node * 64 + cb) = o;
    }
}

// ---------------------------------------------------------------------------
extern "C" void kernel_launch(void* const* d_in, const int* in_sizes, int n_in,
                              void* d_out, int out_size, void* d_ws, size_t ws_size,
                              hipStream_t stream) {
  const float* data = (const float*)d_in[0];
  const int* neigh = (const int*)d_in[1];
  const float* Wa = (const float*)d_in[2];
  const float* gaw = (const float*)d_in[3];
  const float* gab = (const float*)d_in[4];
  const float* Wb = (const float*)d_in[5];
  const float* gbw = (const float*)d_in[6];
  const float* gbb = (const float*)d_in[7];
  const float* W1 = (const float*)d_in[8];
  const float* gsw = (const float*)d_in[9];
  const float* gsb = (const float*)d_in[10];
  float* out = (float*)d_out;

  char* ws = (char*)d_ws;
  _Float16* dpk = (_Float16*)(ws);                  // 102,400,000 B  [N][hi32|lo32]
  _Float16* hhi = (_Float16*)(ws + 102400000);      // 102,400,000 B  [N][64]
  _Float16* hlo = (_Float16*)(ws + 204800000);      // 102,400,000 B  [N][64]
  _Float16* waT = (_Float16*)(ws + 307200000);      //     221,184 B
  _Float16* wbT = (_Float16*)(ws + 307421184);      //     442,368 B
  _Float16* w1T = (_Float16*)(ws + 307863552);      //       8,192 B

  k_split<<<25000, 256, 0, stream>>>(data, dpk, NNODES * CINC / 4);
  k_prepw<<<82, 256, 0, stream>>>(Wa, Wb, W1, waT, wbT, w1T);

  k_conva<<<NNODES / 128, 256, 0, stream>>>(dpk, neigh, waT, gaw, gab, hhi, hlo);
  k_convb<<<NNODES / 128, 256, 0, stream>>>(hhi, hlo, dpk, neigh, wbT, w1T,
                                            gbw, gbb, gsw, gsb, out);
}

// Round 5
// 1615.266 us; speedup vs baseline: 1.1313x; 1.1313x over previous
//
#include <hip/hip_runtime.h>

#define NNODES 800000
#define CINC   32
#define COUTC  64
#define KT     27
#define EPSV   1e-5f

typedef _Float16 half8 __attribute__((ext_vector_type(8)));
typedef _Float16 half4 __attribute__((ext_vector_type(4)));
typedef float    f32x4 __attribute__((ext_vector_type(4)));

#define MFMA(A, B, C) __builtin_amdgcn_mfma_f32_16x16x32_f16((A), (B), (C), 0, 0, 0)
#define SBAR()  __builtin_amdgcn_s_barrier()
#define SCHED() __builtin_amdgcn_sched_barrier(0)
#define NTL(p)     __builtin_nontemporal_load(p)
#define NTS(v, p)  __builtin_nontemporal_store((v), (p))

// Async global->LDS, 16 B per lane: global src per-lane, LDS dst uniform+lane*16.
__device__ __forceinline__ void gl2lds(const _Float16* g, _Float16* l) {
  __builtin_amdgcn_global_load_lds(
      (const __attribute__((address_space(1))) void*)g,
      (__attribute__((address_space(3))) void*)l, 16, 0, 0);
}

// ---------------------------------------------------------------------------
// GroupNorm over one lane-local group of 4 channels (matches jnp reference).
// ---------------------------------------------------------------------------
__device__ __forceinline__ f32x4 gn4(f32x4 v, const float* __restrict__ w,
                                     const float* __restrict__ b, int cb) {
  const float mu = (v[0] + v[1] + v[2] + v[3]) * 0.25f;
  f32x4 d;
#pragma unroll
  for (int j = 0; j < 4; ++j) d[j] = v[j] - mu;
  const float var = (d[0] * d[0] + d[1] * d[1] + d[2] * d[2] + d[3] * d[3]) * 0.25f;
  const float rs = 1.0f / sqrtf(var + EPSV);
  const f32x4 wv = *(const f32x4*)(w + cb);
  const f32x4 bv = *(const f32x4*)(b + cb);
  f32x4 r;
#pragma unroll
  for (int j = 0; j < 4; ++j) r[j] = d[j] * rs * wv[j] + bv[j];
  return r;
}

// ---------------------------------------------------------------------------
// Prepass 1: split f32 -> f16 hi + lo, packed per node (128 B row).
// data read is nt (read-once stream); dpk write is TEMPORAL (gathered later).
// ---------------------------------------------------------------------------
__global__ __launch_bounds__(256) void k_split(const float* __restrict__ x,
                                               _Float16* __restrict__ dpk, int n4) {
  const int i = blockIdx.x * 256 + threadIdx.x;
  if (i >= n4) return;
  const f32x4 v = NTL(&((const f32x4*)x)[i]);
  half4 h, l;
#pragma unroll
  for (int j = 0; j < 4; ++j) {
    h[j] = (_Float16)v[j];
    l[j] = (_Float16)(v[j] - (float)h[j]);
  }
  const int n = i >> 3, g = i & 7;
  *(half4*)(dpk + (size_t)n * 64 + g * 4) = h;
  *(half4*)(dpk + (size_t)n * 64 + 32 + g * 4) = l;
}

// ---------------------------------------------------------------------------
// Prepass 2: pre-swizzle weights into MFMA A-operand image layout.
// waT: [27][t:4][h:2][lane:64][8]  wbT: [27][t:4][kc:2][h:2][lane:64][8]
// ---------------------------------------------------------------------------
__global__ __launch_bounds__(256) void k_prepw(const float* __restrict__ Wa,
                                               const float* __restrict__ Wb,
                                               const float* __restrict__ W1,
                                               _Float16* __restrict__ waT,
                                               _Float16* __restrict__ wbT,
                                               _Float16* __restrict__ w1T) {
  const int u = blockIdx.x * 256 + threadIdx.x;
  const float* s;
  _Float16* d;
  size_t db;
  int cin0, cout;
  if (u < 6912) {
    const int tap = u >> 8, r = u & 255, t = r >> 6, l = r & 63;
    cin0 = (l >> 4) * 8;
    cout = t * 16 + (l & 15);
    s = Wa + (size_t)tap * CINC * COUTC;
    d = waT;
    db = ((size_t)(tap * 8 + t * 2) * 64 + l) * 8;
  } else if (u < 20736) {
    const int u2 = u - 6912;
    const int tap = u2 >> 9, r = u2 & 511, t = r >> 7, r2 = r & 127;
    const int kc = r2 >> 6, l = r2 & 63;
    cin0 = kc * 32 + (l >> 4) * 8;
    cout = t * 16 + (l & 15);
    s = Wb + (size_t)tap * COUTC * COUTC;
    d = wbT;
    db = ((size_t)(tap * 16 + t * 4 + kc * 2) * 64 + l) * 8;
  } else if (u < 20992) {
    const int u3 = u - 20736, t = u3 >> 6, l = u3 & 63;
    cin0 = (l >> 4) * 8;
    cout = t * 16 + (l & 15);
    s = W1;
    d = w1T;
    db = ((size_t)(t * 2) * 64 + l) * 8;
  } else {
    return;
  }
  half8 h, l8;
#pragma unroll
  for (int j = 0; j < 8; ++j) {
    const float v = s[(size_t)(cin0 + j) * COUTC + cout];
    h[j] = (_Float16)v;
    l8[j] = (_Float16)(v - (float)h[j]);
  }
  *(half8*)(d + db) = h;
  *(half8*)(d + db + 512) = l8;
}

// ===========================================================================
// Kernel A: h = relu(GN(conv(data, Wa))) -> packed hpk [N][hi64|lo64] (nt).
// Depth-3 gather prefetch + 3 LDS weight slots, pinned phase edges.
// neigh reads nt, hpk writes nt (streams) -> dpk stays L3-resident.
// ===========================================================================
#define STAGEA(T, SL)                                                          \
  {                                                                            \
    const _Float16* sp_ = waT + (size_t)(T)*4096 + (wave * 2) * 512 + lane * 8;\
    _Float16* dp_ = s_w + (SL)*4096 + (wave * 2) * 512;                        \
    gl2lds(sp_, dp_);                                                          \
    gl2lds(sp_ + 512, dp_ + 512);                                              \
  }

#define GATHA(T, GB)                                                           \
  {                                                                            \
    const int i0_ = s_n[ln0 * KT + (T)];                                       \
    const int i1_ = s_n[(ln0 + 16) * KT + (T)];                                \
    const _Float16* p0_ = dpk + (size_t)i0_ * 64 + q * 8;                      \
    const _Float16* p1_ = dpk + (size_t)i1_ * 64 + q * 8;                      \
    GB[0] = *(const half8*)(p0_);                                              \
    GB[1] = *(const half8*)(p0_ + 32);                                         \
    GB[2] = *(const half8*)(p1_);                                              \
    GB[3] = *(const half8*)(p1_ + 32);                                         \
  }

#define STEPA(T, RS, WS, GBC, GBN, VMS, DOSTAGE, DOG)                          \
  {                                                                            \
    SCHED();                                                                   \
    SBAR();                                                                    \
    SCHED();                                                                   \
    if (DOSTAGE) STAGEA((T) + 2, WS);                                          \
    if (DOG) GATHA((T) + 3, GBN);                                              \
    asm volatile("s_waitcnt vmcnt(" VMS ")" ::: "memory");                     \
    SCHED();                                                                   \
    SBAR();                                                                    \
    SCHED();                                                                   \
    _Pragma("unroll") for (int t4 = 0; t4 < 4; ++t4) {                         \
      const _Float16* wb_ = s_w + (RS)*4096 + (t4 * 2) * 512 + lane * 8;       \
      const half8 wh_ = *(const half8*)(wb_);                                  \
      const half8 wl_ = *(const half8*)(wb_ + 512);                            \
      acc[t4][0] = MFMA(wh_, GBC[0], acc[t4][0]);                              \
      acc[t4][0] = MFMA(wh_, GBC[1], acc[t4][0]);                              \
      acc[t4][0] = MFMA(wl_, GBC[0], acc[t4][0]);                              \
      acc[t4][1] = MFMA(wh_, GBC[2], acc[t4][1]);                              \
      acc[t4][1] = MFMA(wh_, GBC[3], acc[t4][1]);                              \
      acc[t4][1] = MFMA(wl_, GBC[2], acc[t4][1]);                              \
    }                                                                          \
  }

__global__ __launch_bounds__(256, 4) void k_conva(
    const _Float16* __restrict__ dpk, const int* __restrict__ neigh,
    const _Float16* __restrict__ waT, const float* __restrict__ gw,
    const float* __restrict__ gb, _Float16* __restrict__ hpk) {
  __shared__ int s_n[128 * KT];
  __shared__ _Float16 s_w[3 * 4096];  // 3 slots x 8 KB
  const int tid = threadIdx.x;
  const int wave = tid >> 6, lane = tid & 63;
  const int cl = lane & 15, q = lane >> 4;
  const int node0 = blockIdx.x * 128;

  for (int j = tid; j < 128 * KT; j += 256)
    s_n[j] = NTL(&neigh[(size_t)node0 * KT + j]);
  __syncthreads();  // full drain; 0 outstanding entering prologue

  f32x4 acc[4][2] = {};
  const int ln0 = wave * 32 + cl;
  half8 g0[4], g1[4], g2[4], g3[4];

  // Prologue (age order): st(0)->s0, st(1)->s1, G(0), G(1), G(2).
  STAGEA(0, 0);
  STAGEA(1, 1);
  GATHA(0, g0);
  GATHA(1, g1);
  GATHA(2, g2);

  STEPA(0, 0, 2, g0, g3, "14", 1, 1);
  STEPA(1, 1, 0, g1, g0, "16", 1, 1);
  STEPA(2, 2, 1, g2, g1, "16", 1, 1);
  STEPA(3, 0, 2, g3, g2, "16", 1, 1);
  STEPA(4, 1, 0, g0, g3, "16", 1, 1);
  STEPA(5, 2, 1, g1, g0, "16", 1, 1);
  STEPA(6, 0, 2, g2, g1, "16", 1, 1);
  STEPA(7, 1, 0, g3, g2, "16", 1, 1);
  STEPA(8, 2, 1, g0, g3, "16", 1, 1);
  STEPA(9, 0, 2, g1, g0, "16", 1, 1);
  STEPA(10, 1, 0, g2, g1, "16", 1, 1);
  STEPA(11, 2, 1, g3, g2, "16", 1, 1);
  STEPA(12, 0, 2, g0, g3, "16", 1, 1);
  STEPA(13, 1, 0, g1, g0, "16", 1, 1);
  STEPA(14, 2, 1, g2, g1, "16", 1, 1);
  STEPA(15, 0, 2, g3, g2, "16", 1, 1);
  STEPA(16, 1, 0, g0, g3, "16", 1, 1);
  STEPA(17, 2, 1, g1, g0, "16", 1, 1);
  STEPA(18, 0, 2, g2, g1, "16", 1, 1);
  STEPA(19, 1, 0, g3, g2, "16", 1, 1);
  STEPA(20, 2, 1, g0, g3, "16", 1, 1);
  STEPA(21, 0, 2, g1, g0, "16", 1, 1);
  STEPA(22, 1, 0, g2, g1, "16", 1, 1);
  STEPA(23, 2, 1, g3, g2, "16", 1, 1);
  STEPA(24, 0, 2, g0, g3, "12", 1, 0);  // stage(26)->slot2; no gather
  STEPA(25, 1, 0, g1, g0, "6", 0, 0);
  STEPA(26, 2, 1, g2, g1, "0", 0, 0);

#pragma unroll
  for (int t = 0; t < 4; ++t)
#pragma unroll
    for (int nt = 0; nt < 2; ++nt) {
      const int node = node0 + wave * 32 + nt * 16 + cl;
      const int cb = t * 16 + q * 4;
      const f32x4 g = gn4(acc[t][nt], gw, gb, cb);
      half4 h, l;
#pragma unroll
      for (int j = 0; j < 4; ++j) {
        const float v = fmaxf(g[j], 0.0f);
        h[j] = (_Float16)v;
        l[j] = (_Float16)(v - (float)h[j]);
      }
      NTS(h, (half4*)(hpk + (size_t)node * 128 + cb));
      NTS(l, (half4*)(hpk + (size_t)node * 128 + 64 + cb));
    }
}

// ===========================================================================
// Kernel B: out = relu(GN(conv(h, Wb)) + GN(data @ W1)) -> f32.
// Round-3 structure (packed hpk, 12 MFMA/tap, depth-2, pinned phases).
// neigh/dpk reads nt, out writes nt (streams) -> hpk stays L3-resident.
// ===========================================================================
#define STAGEB(T, SL)                                                          \
  {                                                                            \
    const _Float16* sp_ = wbT + (size_t)(T)*8192 + (wave * 4) * 512 + lane * 8;\
    _Float16* dp_ = s_w + (SL)*8192 + (wave * 4) * 512;                        \
    gl2lds(sp_, dp_);                                                          \
    gl2lds(sp_ + 512, dp_ + 512);                                              \
    gl2lds(sp_ + 1024, dp_ + 1024);                                            \
    gl2lds(sp_ + 1536, dp_ + 1536);                                            \
  }

#define GATHB(T, GB)                                                           \
  {                                                                            \
    const int i0_ = s_n[ln0 * KT + (T)];                                       \
    const int i1_ = s_n[(ln0 + 16) * KT + (T)];                                \
    const _Float16* p0_ = hpk + (size_t)i0_ * 128 + q * 8;                     \
    const _Float16* p1_ = hpk + (size_t)i1_ * 128 + q * 8;                     \
    GB[0] = *(const half8*)(p0_);                                              \
    GB[1] = *(const half8*)(p0_ + 32);                                         \
    GB[2] = *(const half8*)(p0_ + 64);                                         \
    GB[3] = *(const half8*)(p0_ + 96);                                         \
    GB[4] = *(const half8*)(p1_);                                              \
    GB[5] = *(const half8*)(p1_ + 32);                                         \
    GB[6] = *(const half8*)(p1_ + 64);                                         \
    GB[7] = *(const half8*)(p1_ + 96);                                         \
  }

#define STEPB(T, S, GBC, GBN, VMS, DOSTAGE, DOG)                               \
  {                                                                            \
    SCHED();                                                                   \
    SBAR();                                                                    \
    SCHED();                                                                   \
    if (DOSTAGE) STAGEB((T) + 1, 1 - (S));                                     \
    if (DOG) GATHB((T) + 2, GBN);                                              \
    asm volatile("s_waitcnt vmcnt(" VMS ")" ::: "memory");                     \
    SCHED();                                                                   \
    SBAR();                                                                    \
    SCHED();                                                                   \
    _Pragma("unroll") for (int t4 = 0; t4 < 4; ++t4) {                         \
      const _Float16* wb_ = s_w + (S)*8192 + (t4 * 4) * 512 + lane * 8;        \
      const half8 wha_ = *(const half8*)(wb_);                                 \
      const half8 wla_ = *(const half8*)(wb_ + 512);                           \
      const half8 whb_ = *(const half8*)(wb_ + 1024);                          \
      const half8 wlb_ = *(const half8*)(wb_ + 1536);                          \
      acc[t4][0] = MFMA(wha_, GBC[0], acc[t4][0]);                             \
      acc[t4][0] = MFMA(wha_, GBC[2], acc[t4][0]);                             \
      acc[t4][0] = MFMA(wla_, GBC[0], acc[t4][0]);                             \
      acc[t4][0] = MFMA(whb_, GBC[1], acc[t4][0]);                             \
      acc[t4][0] = MFMA(whb_, GBC[3], acc[t4][0]);                             \
      acc[t4][0] = MFMA(wlb_, GBC[1], acc[t4][0]);                             \
      acc[t4][1] = MFMA(wha_, GBC[4], acc[t4][1]);                             \
      acc[t4][1] = MFMA(wha_, GBC[6], acc[t4][1]);                             \
      acc[t4][1] = MFMA(wla_, GBC[4], acc[t4][1]);                             \
      acc[t4][1] = MFMA(whb_, GBC[5], acc[t4][1]);                             \
      acc[t4][1] = MFMA(whb_, GBC[7], acc[t4][1]);                             \
      acc[t4][1] = MFMA(wlb_, GBC[5], acc[t4][1]);                             \
    }                                                                          \
  }

__global__ __launch_bounds__(256, 3) void k_convb(
    const _Float16* __restrict__ hpk, const _Float16* __restrict__ dpk,
    const int* __restrict__ neigh, const _Float16* __restrict__ wbT,
    const _Float16* __restrict__ w1T,
    const float* __restrict__ gbw, const float* __restrict__ gbb,
    const float* __restrict__ gsw, const float* __restrict__ gsb,
    float* __restrict__ out) {
  __shared__ int s_n[128 * KT];
  __shared__ _Float16 s_w[2 * 8192];  // 2 slots x 16 KB
  const int tid = threadIdx.x;
  const int wave = tid >> 6, lane = tid & 63;
  const int cl = lane & 15, q = lane >> 4;
  const int node0 = blockIdx.x * 128;

  for (int j = tid; j < 128 * KT; j += 256)
    s_n[j] = NTL(&neigh[(size_t)node0 * KT + j]);
  __syncthreads();

  f32x4 acc[4][2] = {};
  const int ln0 = wave * 32 + cl;
  half8 g0[8], g1[8], g2[8];

  // Prologue: stage(0) 4 gl_lds, G(0)->g0, G(1)->g1  [20 outstanding]
  STAGEB(0, 0);
  GATHB(0, g0);
  GATHB(1, g1);

  // Steady: retain [G(t+1) 8, stage(t+1) 4, G(t+2) 8] = vmcnt(20).
  for (int c6 = 0; c6 < 24; c6 += 6) {
    STEPB(c6 + 0, 0, g0, g2, "20", 1, 1);
    STEPB(c6 + 1, 1, g1, g0, "20", 1, 1);
    STEPB(c6 + 2, 0, g2, g1, "20", 1, 1);
    STEPB(c6 + 3, 1, g0, g2, "20", 1, 1);
    STEPB(c6 + 4, 0, g1, g0, "20", 1, 1);
    STEPB(c6 + 5, 1, g2, g1, "20", 1, 1);
  }
  STEPB(24, 0, g0, g2, "20", 1, 1);
  STEPB(25, 1, g1, g0, "12", 1, 0);
  STEPB(26, 0, g2, g1, "0", 0, 0);

  // Shortcut: sc = data @ W1 (own node; dpk read is a read-once stream -> nt).
  f32x4 sc[4][2] = {};
  {
    const int n0g = node0 + wave * 32 + cl;
    const _Float16* p0 = dpk + (size_t)n0g * 64 + q * 8;
    const _Float16* p1 = dpk + (size_t)(n0g + 16) * 64 + q * 8;
    const half8 sh0 = NTL((const half8*)(p0));
    const half8 sl0 = NTL((const half8*)(p0 + 32));
    const half8 sh1 = NTL((const half8*)(p1));
    const half8 sl1 = NTL((const half8*)(p1 + 32));
    const _Float16* w1p = w1T + lane * 8;
#pragma unroll
    for (int t = 0; t < 4; ++t) {
      const half8 wh = *(const half8*)(w1p + (size_t)(t * 2) * 512);
      const half8 wl = *(const half8*)(w1p + (size_t)(t * 2) * 512 + 512);
      sc[t][0] = MFMA(wh, sh0, sc[t][0]);
      sc[t][0] = MFMA(wh, sl0, sc[t][0]);
      sc[t][0] = MFMA(wl, sh0, sc[t][0]);
      sc[t][1] = MFMA(wh, sh1, sc[t][1]);
      sc[t][1] = MFMA(wh, sl1, sc[t][1]);
      sc[t][1] = MFMA(wl, sh1, sc[t][1]);
    }
  }

#pragma unroll
  for (int t = 0; t < 4; ++t)
#pragma unroll
    for (int nt = 0; nt < 2; ++nt) {
      const int node = node0 + wave * 32 + nt * 16 + cl;
      const int cb = t * 16 + q * 4;
      const f32x4 a = gn4(acc[t][nt], gbw, gbb, cb);
      const f32x4 s = gn4(sc[t][nt], gsw, gsb, cb);
      f32x4 o;
#pragma unroll
      for (int j = 0; j < 4; ++j) o[j] = fmaxf(a[j] + s[j], 0.0f);
      NTS(o, (f32x4*)(out + (size_t)node * 64 + cb));
    }
}

// ---------------------------------------------------------------------------
extern "C" void kernel_launch(void* const* d_in, const int* in_sizes, int n_in,
                              void* d_out, int out_size, void* d_ws, size_t ws_size,
                              hipStream_t stream) {
  const float* data = (const float*)d_in[0];
  const int* neigh = (const int*)d_in[1];
  const float* Wa = (const float*)d_in[2];
  const float* gaw = (const float*)d_in[3];
  const float* gab = (const float*)d_in[4];
  const float* Wb = (const float*)d_in[5];
  const float* gbw = (const float*)d_in[6];
  const float* gbb = (const float*)d_in[7];
  const float* W1 = (const float*)d_in[8];
  const float* gsw = (const float*)d_in[9];
  const float* gsb = (const float*)d_in[10];
  float* out = (float*)d_out;

  char* ws = (char*)d_ws;
  _Float16* dpk = (_Float16*)(ws);                  // 102,400,000 B  [N][hi32|lo32]
  _Float16* hpk = (_Float16*)(ws + 102400000);      // 204,800,000 B  [N][hi64|lo64]
  _Float16* waT = (_Float16*)(ws + 307200000);      //     221,184 B
  _Float16* wbT = (_Float16*)(ws + 307421184);      //     442,368 B
  _Float16* w1T = (_Float16*)(ws + 307863552);      //       8,192 B

  k_split<<<25000, 256, 0, stream>>>(data, dpk, NNODES * CINC / 4);
  k_prepw<<<82, 256, 0, stream>>>(Wa, Wb, W1, waT, wbT, w1T);

  k_conva<<<NNODES / 128, 256, 0, stream>>>(dpk, neigh, waT, gaw, gab, hpk);
  k_convb<<<NNODES / 128, 256, 0, stream>>>(hpk, dpk, neigh, wbT, w1T,
                                            gbw, gbb, gsw, gsb, out);
}